// Round 1
// baseline (1273.414 us; speedup 1.0000x reference)
//
#include <hip/hip_runtime.h>
#include <hip/hip_bf16.h>
#include <math.h>

// Problem constants (from reference): T=2048, B=4096, IN_S=1, H=20, OUT_S=1
#define TT 2048
#define BB 4096
#define HH 20

__device__ __forceinline__ float rcp_fast(float x) {
    return __builtin_amdgcn_rcpf(x);  // v_rcp_f32, ~1 ulp — fine vs 1.5e-3 threshold
}
__device__ __forceinline__ float sigm_fast(float x) {
    // 1/(1+e^-x); e^-x -> inf for very negative x gives 0; -> 0 for large x gives 1. No NaN.
    return rcp_fast(1.0f + __expf(-x));
}
__device__ __forceinline__ float tanh_fast(float x) {
    // tanh(|x|) = (1-e)/(1+e), e = exp(-2|x|) in (0,1] -> no overflow/NaN; restore sign.
    float e = __expf(-2.0f * fabsf(x));
    float t = (1.0f - e) * rcp_fast(1.0f + e);
    return copysignf(t, x);
}

// One wave (64 lanes) per block. Lanes [0..19],[20..39],[40..59] = 3 batches,
// lane -> (batch group, hidden unit j). Lanes 60..63 idle (compute garbage, never store).
__global__ __launch_bounds__(64) void lstm_fused_kernel(
    const float* __restrict__ u,      // [T, B, 1]
    const float* __restrict__ W_ih,   // [4H, 1]
    const float* __restrict__ W_hh,   // [4H, H]
    const float* __restrict__ W_out,  // [1, H]
    float* __restrict__ y)            // [T, B, 1]
{
    __shared__ __align__(16) float hbuf[4][HH];  // row 3 = scratch for idle lanes (80B stride keeps 16B align)

    const int lane  = threadIdx.x;        // 0..63
    const int group = lane / HH;          // 0..3 (3 == idle lanes)
    const int j     = lane - group * HH;  // 0..19
    const int b_real = blockIdx.x * 3 + group;
    const bool active = (group < 3) && (b_real < BB);
    const int b = active ? b_real : 0;    // clamped index for loads (avoid OOB)

    // ---- Load weights into registers (once; L2/L3-cached across blocks) ----
    float w_hh[4][HH];   // rows (g*H + j) of W_hh
    float w_ih[4];
    #pragma unroll
    for (int g = 0; g < 4; ++g) {
        w_ih[g] = W_ih[g * HH + j];
        #pragma unroll
        for (int k = 0; k < HH; ++k)
            w_hh[g][k] = W_hh[(g * HH + j) * HH + k];
    }
    float w_out[HH];
    #pragma unroll
    for (int k = 0; k < HH; ++k) w_out[k] = W_out[k];

    // ---- Recurrent state ----
    float hbc[HH];                        // broadcast copy of full h vector (h_{t-1})
    #pragma unroll
    for (int k = 0; k < HH; ++k) hbc[k] = 0.0f;
    float c = 0.0f;

    const float* __restrict__ up = u + b;       // u[t*B + b]
    float* __restrict__ yp = y + (active ? b_real : 0);

    float u_next = up[0];                       // prefetch t=0

    for (int t = 0; t < TT; ++t) {
        const float uv = u_next;
        // Prefetch next timestep's u early so its ~200-900cy latency overlaps compute.
        const int tn = (t + 1 < TT) ? (t + 1) : t;
        u_next = up[(size_t)tn * BB];

        // gates[g] = u*W_ih[g*H+j] + sum_k W_hh[g*H+j][k] * h_{t-1}[k]
        float acc0 = uv * w_ih[0];
        float acc1 = uv * w_ih[1];
        float acc2 = uv * w_ih[2];
        float acc3 = uv * w_ih[3];
        #pragma unroll
        for (int k = 0; k < HH; ++k) {
            acc0 = fmaf(w_hh[0][k], hbc[k], acc0);
            acc1 = fmaf(w_hh[1][k], hbc[k], acc1);
            acc2 = fmaf(w_hh[2][k], hbc[k], acc2);
            acc3 = fmaf(w_hh[3][k], hbc[k], acc3);
        }

        const float ig = sigm_fast(acc0);
        const float fg = sigm_fast(acc1);
        const float gg = tanh_fast(acc2);
        const float og = sigm_fast(acc3);
        c = fmaf(fg, c, ig * gg);
        const float h = og * tanh_fast(c);

        // ---- Broadcast h_t across the 20-lane group via LDS ----
        hbuf[group][j] = h;
        __syncthreads();   // single-wave block: compiles to lgkmcnt drain + cheap barrier
        float4 q0 = ((const float4*)(&hbuf[group][0]))[0];
        float4 q1 = ((const float4*)(&hbuf[group][0]))[1];
        float4 q2 = ((const float4*)(&hbuf[group][0]))[2];
        float4 q3 = ((const float4*)(&hbuf[group][0]))[3];
        float4 q4 = ((const float4*)(&hbuf[group][0]))[4];
        hbc[0]=q0.x; hbc[1]=q0.y; hbc[2]=q0.z; hbc[3]=q0.w;
        hbc[4]=q1.x; hbc[5]=q1.y; hbc[6]=q1.z; hbc[7]=q1.w;
        hbc[8]=q2.x; hbc[9]=q2.y; hbc[10]=q2.z; hbc[11]=q2.w;
        hbc[12]=q3.x; hbc[13]=q3.y; hbc[14]=q3.z; hbc[15]=q3.w;
        hbc[16]=q4.x; hbc[17]=q4.y; hbc[18]=q4.z; hbc[19]=q4.w;
        __syncthreads();   // protect hbuf WAR before next iteration's write

        // y_t = W_out . h_t  (computed redundantly on all lanes; lane j==0 stores)
        float yv = 0.0f;
        #pragma unroll
        for (int k = 0; k < HH; ++k) yv = fmaf(w_out[k], hbc[k], yv);
        if (active && j == 0) yp[(size_t)t * BB] = yv;
    }
}

extern "C" void kernel_launch(void* const* d_in, const int* in_sizes, int n_in,
                              void* d_out, int out_size, void* d_ws, size_t ws_size,
                              hipStream_t stream) {
    const float* u     = (const float*)d_in[0];   // [2048, 4096, 1]
    const float* W_ih  = (const float*)d_in[1];   // [80, 1]
    const float* W_hh  = (const float*)d_in[2];   // [80, 20]
    const float* W_out = (const float*)d_in[3];   // [1, 20]
    float* y = (float*)d_out;                      // [2048, 4096, 1]

    const int blocks = (BB + 2) / 3;  // 3 batches per 64-thread (1-wave) block -> 1366
    lstm_fused_kernel<<<dim3(blocks), dim3(64), 0, stream>>>(u, W_ih, W_hh, W_out, y);
}

// Round 2
// 1102.803 us; speedup vs baseline: 1.1547x; 1.1547x over previous
//
#include <hip/hip_runtime.h>
#include <hip/hip_bf16.h>
#include <math.h>

// Problem constants (from reference): T=2048, B=4096, IN_S=1, H=20, OUT_S=1
#define TT 2048
#define BB 4096
#define HH 20

__device__ __forceinline__ float rcp_fast(float x) {
    return __builtin_amdgcn_rcpf(x);  // v_rcp_f32, ~1 ulp — fine vs 1.5e-3 threshold
}
__device__ __forceinline__ float sigm_fast(float x) {
    return rcp_fast(1.0f + __expf(-x));
}
__device__ __forceinline__ float tanh_fast(float x) {
    // tanh(|x|) = (1-e)/(1+e), e = exp(-2|x|) in (0,1] -> no overflow/NaN; restore sign.
    float e = __expf(-2.0f * fabsf(x));
    float t = (1.0f - e) * rcp_fast(1.0f + e);
    return copysignf(t, x);
}

// One wave (64 lanes) per block. Lanes [0..19],[20..39],[40..59] = 3 batches,
// lane -> (batch group, hidden unit j). Lanes 60..63 idle (compute garbage, never store).
// __launch_bounds__(64, 1): grid gives only ~1.33 waves/SIMD anyway — let the
// compiler use up to 512 VGPRs so w_hh/w_out/hbc all stay in VGPRs (prev build
// reported VGPR_Count=60 -> weight arrays were demoted; issue count exploded).
__global__ __launch_bounds__(64, 1) void lstm_fused_kernel(
    const float* __restrict__ u,      // [T, B, 1]
    const float* __restrict__ W_ih,   // [4H, 1]
    const float* __restrict__ W_hh,   // [4H, H]
    const float* __restrict__ W_out,  // [1, H]
    float* __restrict__ y)            // [T, B, 1]
{
    // Double-buffered by step parity: removes the WAR barrier between the
    // broadcast read of step t and the write of step t+1.
    __shared__ __align__(16) float hbuf[2][4][HH];

    const int lane  = threadIdx.x;        // 0..63
    const int group = lane / HH;          // 0..3 (3 == idle lanes)
    const int j     = lane - group * HH;  // 0..19
    const int b_real = blockIdx.x * 3 + group;
    const bool active = (group < 3) && (b_real < BB);
    const int b = active ? b_real : 0;    // clamped index for loads (avoid OOB)

    // ---- Load weights into registers ----
    float w_hh[4][HH];
    float w_ih[4];
    #pragma unroll
    for (int g = 0; g < 4; ++g) {
        w_ih[g] = W_ih[g * HH + j];
        #pragma unroll
        for (int k = 0; k < HH; ++k)
            w_hh[g][k] = W_hh[(g * HH + j) * HH + k];
    }
    float w_out[HH];
    #pragma unroll
    for (int k = 0; k < HH; ++k) w_out[k] = W_out[k];

    // ---- Recurrent state ----
    float hbc[HH];
    #pragma unroll
    for (int k = 0; k < HH; ++k) hbc[k] = 0.0f;
    float c = 0.0f;

    const float* __restrict__ up = u + b;
    float* __restrict__ yp = y + b;       // stored only by active j==0 lanes

    // Prefetch first 4 timesteps of u.
    float u_cur[4];
    #pragma unroll
    for (int k = 0; k < 4; ++k) u_cur[k] = up[(size_t)k * BB];

    for (int t4 = 0; t4 < TT; t4 += 4) {
        // Kick off next chunk's u loads now; they have the whole 4-step body
        // (~1k+ cycles) to land. Clamp at the end (reload of last chunk, unused).
        const int tn = (t4 + 4 < TT) ? (t4 + 4) : t4;
        float u_nxt[4];
        #pragma unroll
        for (int k = 0; k < 4; ++k) u_nxt[k] = up[(size_t)(tn + k) * BB];

        float y4[4];

        #pragma unroll
        for (int tt = 0; tt < 4; ++tt) {
            const float uv = u_cur[tt];

            // gates[g] = u*w_ih[g] + sum_k w_hh[g][k] * h_{t-1}[k]
            float a0 = uv * w_ih[0];
            float a1 = uv * w_ih[1];
            float a2 = uv * w_ih[2];
            float a3 = uv * w_ih[3];
            #pragma unroll
            for (int k = 0; k < HH; ++k) {
                a0 = fmaf(w_hh[0][k], hbc[k], a0);
                a1 = fmaf(w_hh[1][k], hbc[k], a1);
                a2 = fmaf(w_hh[2][k], hbc[k], a2);
                a3 = fmaf(w_hh[3][k], hbc[k], a3);
            }

            const float ig = sigm_fast(a0);
            const float fg = sigm_fast(a1);
            const float gg = tanh_fast(a2);
            const float og = sigm_fast(a3);
            c = fmaf(fg, c, ig * gg);
            const float h = og * tanh_fast(c);

            // ---- Broadcast h_t across the 20-lane group via LDS ----
            // Single-wave block: the DS pipe processes this wave's ops in
            // order, so write -> lgkmcnt(0) -> read gives cross-lane
            // visibility WITHOUT s_barrier (and without the vmcnt(0) drain
            // __syncthreads would impose on the y-stores / u-loads).
            const int p = tt & 1;
            hbuf[p][group][j] = h;
            asm volatile("s_waitcnt lgkmcnt(0)" ::: "memory");
            const float4* __restrict__ src = (const float4*)(&hbuf[p][group][0]);
            float4 q0 = src[0];
            float4 q1 = src[1];
            float4 q2 = src[2];
            float4 q3 = src[3];
            float4 q4 = src[4];
            asm volatile("s_waitcnt lgkmcnt(0)" ::: "memory");
            hbc[0]=q0.x;  hbc[1]=q0.y;  hbc[2]=q0.z;  hbc[3]=q0.w;
            hbc[4]=q1.x;  hbc[5]=q1.y;  hbc[6]=q1.z;  hbc[7]=q1.w;
            hbc[8]=q2.x;  hbc[9]=q2.y;  hbc[10]=q2.z; hbc[11]=q2.w;
            hbc[12]=q3.x; hbc[13]=q3.y; hbc[14]=q3.z; hbc[15]=q3.w;
            hbc[16]=q4.x; hbc[17]=q4.y; hbc[18]=q4.z; hbc[19]=q4.w;

            // y_t = W_out . h_t (redundant across lanes; only j==0 stores)
            float yv = 0.0f;
            #pragma unroll
            for (int k = 0; k < HH; ++k) yv = fmaf(w_out[k], hbc[k], yv);
            y4[tt] = yv;
        }

        // Batched y stores — off the per-step critical path.
        if (active && j == 0) {
            #pragma unroll
            for (int k = 0; k < 4; ++k) yp[(size_t)(t4 + k) * BB] = y4[k];
        }

        #pragma unroll
        for (int k = 0; k < 4; ++k) u_cur[k] = u_nxt[k];
    }
}

extern "C" void kernel_launch(void* const* d_in, const int* in_sizes, int n_in,
                              void* d_out, int out_size, void* d_ws, size_t ws_size,
                              hipStream_t stream) {
    const float* u     = (const float*)d_in[0];   // [2048, 4096, 1]
    const float* W_ih  = (const float*)d_in[1];   // [80, 1]
    const float* W_hh  = (const float*)d_in[2];   // [80, 20]
    const float* W_out = (const float*)d_in[3];   // [1, 20]
    float* y = (float*)d_out;                      // [2048, 4096, 1]

    const int blocks = (BB + 2) / 3;  // 3 batches per 64-thread (1-wave) block -> 1366
    lstm_fused_kernel<<<dim3(blocks), dim3(64), 0, stream>>>(u, W_ih, W_hh, W_out, y);
}